// Round 16
// baseline (217.297 us; speedup 1.0000x reference)
//
#include <hip/hip_runtime.h>
#include <hip/hip_bf16.h>

typedef __bf16 bf16_t;
typedef __bf16 bf16x8 __attribute__((ext_vector_type(8)));
typedef __bf16 bf16x4 __attribute__((ext_vector_type(4)));
typedef float f32x4 __attribute__((ext_vector_type(4)));
typedef float f32x16 __attribute__((ext_vector_type(16)));

// 1/sqrt(128) * log2(e)  (folded into Q so that P = exp2(S))
#define SCALE_Q2 0.12752518895325724f

__device__ __forceinline__ void gload_lds16(const void* g, void* l) {
  __builtin_amdgcn_global_load_lds(
      (const __attribute__((address_space(1))) void*)g,
      (__attribute__((address_space(3))) void*)l, 16, 0, 0);
}

// ---------------- fused fp32 -> bf16 converts (x | wq|wk|wv | wo) ----------
__global__ __launch_bounds__(256) void cvt_all(
    const float* __restrict__ x, const float* __restrict__ wq,
    const float* __restrict__ wk, const float* __restrict__ wv,
    const float* __restrict__ wo, bf16_t* __restrict__ xb,
    bf16_t* __restrict__ wqkv, bf16_t* __restrict__ wo_b) {
  int i = blockIdx.x * 256 + threadIdx.x;
  const int stride = gridDim.x * 256;
  for (; i < 4718592; i += stride) {
    const int e = i * 4;
    const float* src;
    bf16_t* dst;
    if (e < 8388608) {
      src = x + e;              dst = xb + e;
    } else if (e < 12582912) {
      src = wq + (e - 8388608); dst = wqkv + (e - 8388608);
    } else if (e < 13631488) {
      src = wk + (e - 12582912); dst = wqkv + (e - 8388608);
    } else if (e < 14680064) {
      src = wv + (e - 13631488); dst = wqkv + (e - 8388608);
    } else {
      src = wo + (e - 14680064); dst = wo_b + (e - 14680064);
    }
    f32x4 v = *reinterpret_cast<const f32x4*>(src);
    bf16x4 r;
    r[0] = (bf16_t)v[0]; r[1] = (bf16_t)v[1];
    r[2] = (bf16_t)v[2]; r[3] = (bf16_t)v[3];
    *reinterpret_cast<bf16x4*>(dst) = r;
  }
}

// ---------------- bf16 GEMM:  C[M][N] = A[M][K] * W[N][K]^T ----------------
// BK=64, DOUBLE-buffered (64KB LDS, 2 blocks/CU) with attn-proven ordering:
// sync -> STAGE(next) -> compute(cur). The barrier's vmcnt drain then waits
// on loads that had a full compute phase to land (vs fully-exposed staging
// in the single-buffered r15 version). XOR involution swizzle as r15.
template <typename OutT>
__global__ __launch_bounds__(256) void gemm_bt(
    const bf16_t* __restrict__ A, const bf16_t* __restrict__ W,
    OutT* __restrict__ C, int M, int N, int K) {
  __shared__ __align__(16) bf16_t As[2][128 * 64];
  __shared__ __align__(16) bf16_t Ws[2][128 * 64];
  const int tid = threadIdx.x;
  const int lane = tid & 63;
  const int wid = tid >> 6;
  const int wr = wid >> 1, wc = wid & 1;
  const int l15 = lane & 15, lg = lane >> 4;
  const int r0 = blockIdx.y * 128;
  const int c0 = blockIdx.x * 128;

  f32x4 acc[4][4];
#pragma unroll
  for (int mi = 0; mi < 4; ++mi)
#pragma unroll
    for (int ni = 0; ni < 4; ++ni)
#pragma unroll
      for (int j = 0; j < 4; ++j) acc[mi][ni][j] = 0.f;

  auto STAGE = [&](int buf, int k0) {
#pragma unroll
    for (int s = 0; s < 4; ++s) {
      const int c = s * 256 + tid;            // 16B-chunk id [0,1024)
      const int row = c >> 3;
      const int scol = (c & 7) ^ (row & 7);   // pre-swizzled source chunk
      gload_lds16(A + (size_t)(r0 + row) * K + k0 + scol * 8,
                  (char*)As[buf] + c * 16);
      gload_lds16(W + (size_t)(c0 + row) * K + k0 + scol * 8,
                  (char*)Ws[buf] + c * 16);
    }
  };

  const int nt = K >> 6;
  STAGE(0, 0);
  int cur = 0;
  for (int t = 0; t < nt; ++t) {
    __syncthreads();  // drains STAGE(cur); prev compute of cur^1 done
    if (t + 1 < nt) STAGE(cur ^ 1, (t + 1) * 64);
#pragma unroll
    for (int kk = 0; kk < 2; ++kk) {
      bf16x8 af[4], wf[4];
#pragma unroll
      for (int mi = 0; mi < 4; ++mi) {
        const int r = wr * 64 + mi * 16 + l15;
        af[mi] = *reinterpret_cast<const bf16x8*>(
            (char*)As[cur] + r * 128 + ((kk * 64 + lg * 16) ^ ((r & 7) << 4)));
      }
#pragma unroll
      for (int ni = 0; ni < 4; ++ni) {
        const int r = wc * 64 + ni * 16 + l15;
        wf[ni] = *reinterpret_cast<const bf16x8*>(
            (char*)Ws[cur] + r * 128 + ((kk * 64 + lg * 16) ^ ((r & 7) << 4)));
      }
#pragma unroll
      for (int mi = 0; mi < 4; ++mi)
#pragma unroll
        for (int ni = 0; ni < 4; ++ni)
          acc[mi][ni] = __builtin_amdgcn_mfma_f32_16x16x32_bf16(
              af[mi], wf[ni], acc[mi][ni], 0, 0, 0);
    }
    cur ^= 1;
  }

#pragma unroll
  for (int mi = 0; mi < 4; ++mi)
#pragma unroll
    for (int ni = 0; ni < 4; ++ni)
#pragma unroll
      for (int j = 0; j < 4; ++j) {
        const int row = r0 + wr * 64 + mi * 16 + lg * 4 + j;
        const int col = c0 + wc * 64 + ni * 16 + l15;
        const float v = acc[mi][ni][j];
        if constexpr (__is_same(OutT, float))
          C[(size_t)row * N + col] = v;
        else
          C[(size_t)row * N + col] = (bf16_t)v;
      }
}

// ---------------- fused RoPE + V transpose ----------------
// blocks [0,4096): RoPE qkv -> Qr (pre-scaled), Kr (coalesced both ways)
// blocks [4096,4608): LDS-tiled V transpose -> Vt[B*4][128][2048], token
// columns permuted within 16-groups (swap bits 2<->3 of t&15).
__global__ __launch_bounds__(256) void rope_vtrans(
    const bf16_t* __restrict__ qkv, const float* __restrict__ fc,
    const float* __restrict__ fs, bf16_t* __restrict__ Qr,
    bf16_t* __restrict__ Kr, bf16_t* __restrict__ Vt) {
  __shared__ bf16_t L[64][68];
  const int tid = threadIdx.x;
  if (blockIdx.x < 4096) {
    const int n = blockIdx.x;
    const int b = n >> 11, t = n & 2047;
    const bf16_t* row = qkv + (size_t)n * 3072;
#pragma unroll
    for (int i = 0; i < 4; ++i) {
      const int p = i * 256 + tid;
      const int h = p >> 6, j = p & 63;
      const float t0 = (float)row[h * 128 + 2 * j];
      const float t1 = (float)row[h * 128 + 2 * j + 1];
      const float c = fc[t * 64 + j], s = fs[t * 64 + j];
      const size_t dst = ((size_t)(b * 16 + h) * 2048 + t) * 128 + 2 * j;
      Qr[dst] = (bf16_t)((t0 * c - t1 * s) * SCALE_Q2);
      Qr[dst + 1] = (bf16_t)((t0 * s + t1 * c) * SCALE_Q2);
    }
    {
      const int kvh = tid >> 6, j = tid & 63;
      const float t0 = (float)row[2048 + kvh * 128 + 2 * j];
      const float t1 = (float)row[2048 + kvh * 128 + 2 * j + 1];
      const float c = fc[t * 64 + j], s = fs[t * 64 + j];
      const size_t dst = ((size_t)(b * 4 + kvh) * 2048 + t) * 128 + 2 * j;
      Kr[dst] = (bf16_t)(t0 * c - t1 * s);
      Kr[dst + 1] = (bf16_t)(t0 * s + t1 * c);
    }
  } else {
    const int bid = blockIdx.x - 4096;       // [0,512)
    const int tt = bid & 31;
    const int dt2 = (bid >> 5) & 1;
    const int bk = bid >> 6;
    const int b = bk >> 2, kvh = bk & 3;
    const int t0 = tt * 64, d0 = dt2 * 64;
    const int r = tid >> 4;
    const int c4 = (tid & 15) * 4;
#pragma unroll
    for (int it = 0; it < 4; ++it) {
      const int tl = r + it * 16;
      const int tp = (tl & ~15) |
                     ((tl & 3) | ((tl & 4) << 1) | ((tl & 8) >> 1));
      const bf16_t* src = qkv + (size_t)(b * 2048 + t0 + tl) * 3072 + 2560 +
                          kvh * 128 + d0 + c4;
      *reinterpret_cast<bf16x4*>(&L[tp][c4]) =
          *reinterpret_cast<const bf16x4*>(src);
    }
    __syncthreads();
#pragma unroll
    for (int it = 0; it < 4; ++it) {
      const int dr = r + it * 16;
      bf16x4 v;
#pragma unroll
      for (int j = 0; j < 4; ++j) v[j] = L[c4 + j][dr];
      *reinterpret_cast<bf16x4*>(Vt + ((size_t)bk * 128 + d0 + dr) * 2048 +
                                 t0 + c4) = v;
    }
  }
}

// ---------------- causal GQA flash attention (32x32 MFMA, swapped QK) ------
// Round-15 structure + lsum via ones-MFMA: the 15-deep VALU add tree per
// quarter moves to the MFMA pipe (mfma(ones, pb, osum); every D row holds
// the col-sum, so ltot = osum[0], no final shfl). +16 VGPR (~143), safe
// under (256,2).
#define VLOAD(buf, kf, kc)                                               \
  {                                                                      \
    _Pragma("unroll") for (int dtile_ = 0; dtile_ < 4; ++dtile_)         \
        buf[dtile_] = *reinterpret_cast<const bf16x8*>(                  \
            Vbase + (size_t)(dtile_ * 32 + l31) * 2048 + k0 + (kf) * 32 +\
            (kc) * 16 + hi * 8);                                         \
  }

__global__ __launch_bounds__(256, 2) void attn_fwd(
    const bf16_t* __restrict__ Qr, const bf16_t* __restrict__ Kr,
    const bf16_t* __restrict__ Vt, bf16_t* __restrict__ Oout) {
  __shared__ __align__(16) bf16_t Klds[2][128 * 128];
  const int tid = threadIdx.x;
  const int lane = tid & 63, w = tid >> 6;
  const int l31 = lane & 31, hi = lane >> 5;
  const int sidx = blockIdx.x >> 5;
  const int hb = blockIdx.x & 31;
  const int h = hb & 15, b = hb >> 4;
  const int kvh = h >> 2;
  const int st = (sidx < 8) ? (15 - sidx) : (sidx - 8);

  const bf16_t* Kbase = Kr + ((size_t)(b * 4 + kvh) * 2048) * 128;
  const bf16_t* Vbase = Vt + ((size_t)(b * 4 + kvh) * 128) * 2048;

  const int qbw = st * 128 + w * 32;
  const bf16_t* Qbase = Qr + ((size_t)(b * 16 + h) * 2048 + qbw + l31) * 128;

  auto STAGE = [&](bf16_t* dst, int kt) {
    const int k0s = kt * 128;
#pragma unroll
    for (int i = 0; i < 8; ++i) {
      const int c = i * 256 + tid;
      const int row = c >> 4;
      const int col = c & 15;
      const int scol = col ^ (row & 15);
      gload_lds16(Kbase + (size_t)(k0s + row) * 128 + scol * 8, dst + c * 8);
    }
  };

  STAGE(&Klds[0][0], 0);

  bf16x8 qf[8];
#pragma unroll
  for (int dt = 0; dt < 8; ++dt)
    qf[dt] = *reinterpret_cast<const bf16x8*>(Qbase + dt * 16 + hi * 8);

  bf16x8 onesv;
#pragma unroll
  for (int i = 0; i < 8; ++i) onesv[i] = (bf16_t)1.0f;

  f32x16 o[4];
#pragma unroll
  for (int d = 0; d < 4; ++d)
#pragma unroll
    for (int r = 0; r < 16; ++r) o[d][r] = 0.f;
  f32x16 osum;
#pragma unroll
  for (int r = 0; r < 16; ++r) osum[r] = 0.f;

  const int nt = st + 1;
  int cur = 0;
  for (int kt = 0; kt < nt; ++kt) {
    const int k0 = kt * 128;
    const bool last = (kt == nt - 1);
    const int kfmax = last ? w : 3;

    __syncthreads();  // prev STAGE drained; all readers of other buf done
    if (kt + 1 < nt) STAGE(&Klds[cur ^ 1][0], kt + 1);

    const char* KB = (const char*)&Klds[cur][0];

    // prologue V prefetch for kf=0 (lands under QK pair 0)
    bf16x8 vaA[4], vaB[4];
    VLOAD(vaA, 0, 0);
    VLOAD(vaB, 0, 1);

#pragma unroll
    for (int kp = 0; kp < 2; ++kp) {
      // ---- QK^T for kf pair (2kp, 2kp+1): two independent MFMA chains ----
      f32x16 sA, sB;
      __builtin_amdgcn_s_setprio(1);
      if (2 * kp <= kfmax) {
#pragma unroll
        for (int r = 0; r < 16; ++r) sA[r] = 0.f;
#pragma unroll
        for (int dt = 0; dt < 8; ++dt) {
          const int boff = ((2 * kp) * 32 + l31) * 256 +
                           ((dt * 32 + hi * 16) ^ ((l31 & 15) << 4));
          bf16x8 ka = *reinterpret_cast<const bf16x8*>(KB + boff);
          sA = __builtin_amdgcn_mfma_f32_32x32x16_bf16(ka, qf[dt], sA, 0, 0, 0);
        }
      }
      if (2 * kp + 1 <= kfmax) {
#pragma unroll
        for (int r = 0; r < 16; ++r) sB[r] = 0.f;
#pragma unroll
        for (int dt = 0; dt < 8; ++dt) {
          const int boff = ((2 * kp + 1) * 32 + l31) * 256 +
                           ((dt * 32 + hi * 16) ^ ((l31 & 15) << 4));
          bf16x8 ka = *reinterpret_cast<const bf16x8*>(KB + boff);
          sB = __builtin_amdgcn_mfma_f32_32x32x16_bf16(ka, qf[dt], sB, 0, 0, 0);
        }
      }
      __builtin_amdgcn_s_setprio(0);

      // ---- softmax + PV per kf in the pair ----
#pragma unroll
      for (int ki = 0; ki < 2; ++ki) {
        const int kf = 2 * kp + ki;
        if (kf <= kfmax) {
          const bool diag = last && (kf == w);
          float p[16];
#pragma unroll
          for (int r = 0; r < 16; ++r) {
            float e = exp2f(ki ? sB[r] : sA[r]);
            if (diag) {
              const int crow = (r & 3) + 8 * (r >> 2) + 4 * hi;
              if (crow > l31) e = 0.f;
            }
            p[r] = e;
          }

          // kc0: consume vaA, then reload it for kf+1
          {
            unsigned int u0, u1, u2, u3;
            asm("v_cvt_pk_bf16_f32 %0, %1, %2" : "=v"(u0)
                : "v"(p[0]), "v"(p[1]));
            asm("v_cvt_pk_bf16_f32 %0, %1, %2" : "=v"(u1)
                : "v"(p[2]), "v"(p[3]));
            asm("v_cvt_pk_bf16_f32 %0, %1, %2" : "=v"(u2)
                : "v"(p[4]), "v"(p[5]));
            asm("v_cvt_pk_bf16_f32 %0, %1, %2" : "=v"(u3)
                : "v"(p[6]), "v"(p[7]));
            union { unsigned int u[4]; bf16x8 v; } pb;
            pb.u[0] = u0; pb.u[1] = u1; pb.u[2] = u2; pb.u[3] = u3;
            __builtin_amdgcn_s_setprio(1);
            osum = __builtin_amdgcn_mfma_f32_32x32x16_bf16(onesv, pb.v, osum,
                                                           0, 0, 0);
#pragma unroll
            for (int dtile = 0; dtile < 4; ++dtile)
              o[dtile] = __builtin_amdgcn_mfma_f32_32x32x16_bf16(
                  vaA[dtile], pb.v, o[dtile], 0, 0, 0);
            __builtin_amdgcn_s_setprio(0);
          }
          if (kf < kfmax) VLOAD(vaA, kf + 1, 0);

          // kc1: consume vaB, then reload it for kf+1
          {
            unsigned int u0, u1, u2, u3;
            asm("v_cvt_pk_bf16_f32 %0, %1, %2" : "=v"(u0)
                : "v"(p[8]), "v"(p[9]));
            asm("v_cvt_pk_bf16_f32 %0, %1, %2" : "=v"(u1)
                : "v"(p[10]), "v"(p[11]));
            asm("v_cvt_pk_bf16_f32 %0, %1, %2" : "=v"(u2)
                : "v"(p[12]), "v"(p[13]));
            asm("v_cvt_pk_bf16_f32 %0, %1, %2" : "=v"(u3)
                : "v"(p[14]), "v"(p[15]));
            union { unsigned int u[4]; bf16x8 v; } pb;
            pb.u[0] = u0; pb.u[1] = u1; pb.u[2] = u2; pb.u[3] = u3;
            __builtin_amdgcn_s_setprio(1);
            osum = __builtin_amdgcn_mfma_f32_32x32x16_bf16(onesv, pb.v, osum,
                                                           0, 0, 0);
#pragma unroll
            for (int dtile = 0; dtile < 4; ++dtile)
              o[dtile] = __builtin_amdgcn_mfma_f32_32x32x16_bf16(
                  vaB[dtile], pb.v, o[dtile], 0, 0, 0);
            __builtin_amdgcn_s_setprio(0);
          }
          if (kf < kfmax) VLOAD(vaB, kf + 1, 1);
        }
      }
    }
    cur ^= 1;
  }

  // ---- epilogue: normalize + store O^T (col=q, row=d) ----
  const float inv = 1.f / osum[0];   // every D row holds the col-sum
  bf16_t* Obase = Oout + ((size_t)b * 2048 + qbw + l31) * 2048 + h * 128;
#pragma unroll
  for (int dtile = 0; dtile < 4; ++dtile)
#pragma unroll
    for (int g = 0; g < 4; ++g) {
      bf16x4 stv;
#pragma unroll
      for (int j = 0; j < 4; ++j)
        stv[j] = (bf16_t)(o[dtile][g * 4 + j] * inv);
      *reinterpret_cast<bf16x4*>(Obase + dtile * 32 + 8 * g + 4 * hi) = stv;
    }
}

// ---------------- host launch ----------------
extern "C" void kernel_launch(void* const* d_in, const int* in_sizes, int n_in,
                              void* d_out, int out_size, void* d_ws,
                              size_t ws_size, hipStream_t stream) {
  const float* x  = (const float*)d_in[0];
  const float* wq = (const float*)d_in[1];
  const float* wk = (const float*)d_in[2];
  const float* wv = (const float*)d_in[3];
  const float* wo = (const float*)d_in[4];
  const float* fc = (const float*)d_in[5];
  const float* fs = (const float*)d_in[6];
  float* out = (float*)d_out;

  char* ws = (char*)d_ws;
  bf16_t* xb      = (bf16_t*)(ws + 0);
  bf16_t* wqkv    = (bf16_t*)(ws + 16777216);
  bf16_t* wo_b    = (bf16_t*)(ws + 29360128);
  bf16_t* qkv     = (bf16_t*)(ws + 37748736);
  bf16_t* Qr      = (bf16_t*)(ws + 62914560);
  bf16_t* Kr      = (bf16_t*)(ws + 79691776);
  bf16_t* Vt      = (bf16_t*)(ws + 83886080);
  bf16_t* attn_o  = xb;

  const int M = 4096;

  cvt_all<<<2048, 256, 0, stream>>>(x, wq, wk, wv, wo, xb, wqkv, wo_b);

  gemm_bt<bf16_t><<<dim3(3072 / 128, M / 128), 256, 0, stream>>>(
      xb, wqkv, qkv, M, 3072, 2048);

  rope_vtrans<<<4608, 256, 0, stream>>>(qkv, fc, fs, Qr, Kr, Vt);

  attn_fwd<<<512, 256, 0, stream>>>(Qr, Kr, Vt, attn_o);

  gemm_bt<float><<<dim3(2048 / 128, M / 128), 256, 0, stream>>>(
      attn_o, wo_b, out, M, 2048, 2048);
}

// Round 17
// 212.472 us; speedup vs baseline: 1.0227x; 1.0227x over previous
//
#include <hip/hip_runtime.h>
#include <hip/hip_bf16.h>

typedef __bf16 bf16_t;
typedef __bf16 bf16x8 __attribute__((ext_vector_type(8)));
typedef __bf16 bf16x4 __attribute__((ext_vector_type(4)));
typedef float f32x4 __attribute__((ext_vector_type(4)));
typedef float f32x16 __attribute__((ext_vector_type(16)));

// 1/sqrt(128) * log2(e)  (folded into Q so that P = exp2(S))
#define SCALE_Q2 0.12752518895325724f

__device__ __forceinline__ void gload_lds16(const void* g, void* l) {
  __builtin_amdgcn_global_load_lds(
      (const __attribute__((address_space(1))) void*)g,
      (__attribute__((address_space(3))) void*)l, 16, 0, 0);
}

// ---------------- fused fp32 -> bf16 converts (x | wq|wk|wv | wo) ----------
__global__ __launch_bounds__(256) void cvt_all(
    const float* __restrict__ x, const float* __restrict__ wq,
    const float* __restrict__ wk, const float* __restrict__ wv,
    const float* __restrict__ wo, bf16_t* __restrict__ xb,
    bf16_t* __restrict__ wqkv, bf16_t* __restrict__ wo_b) {
  int i = blockIdx.x * 256 + threadIdx.x;
  const int stride = gridDim.x * 256;
  for (; i < 4718592; i += stride) {
    const int e = i * 4;
    const float* src;
    bf16_t* dst;
    if (e < 8388608) {
      src = x + e;              dst = xb + e;
    } else if (e < 12582912) {
      src = wq + (e - 8388608); dst = wqkv + (e - 8388608);
    } else if (e < 13631488) {
      src = wk + (e - 12582912); dst = wqkv + (e - 8388608);
    } else if (e < 14680064) {
      src = wv + (e - 13631488); dst = wqkv + (e - 8388608);
    } else {
      src = wo + (e - 14680064); dst = wo_b + (e - 14680064);
    }
    f32x4 v = *reinterpret_cast<const f32x4*>(src);
    bf16x4 r;
    r[0] = (bf16_t)v[0]; r[1] = (bf16_t)v[1];
    r[2] = (bf16_t)v[2]; r[3] = (bf16_t)v[3];
    *reinterpret_cast<bf16x4*>(dst) = r;
  }
}

// ---------------- bf16 GEMM:  C[M][N] = A[M][K] * W[N][K]^T ----------------
// BK=64, double-buffered (64KB LDS): sync -> STAGE(next) -> compute(cur).
// XOR involution swizzle (16B-chunk ^ row&7), source pre-swizzled.
template <typename OutT>
__global__ __launch_bounds__(256) void gemm_bt(
    const bf16_t* __restrict__ A, const bf16_t* __restrict__ W,
    OutT* __restrict__ C, int M, int N, int K) {
  __shared__ __align__(16) bf16_t As[2][128 * 64];
  __shared__ __align__(16) bf16_t Ws[2][128 * 64];
  const int tid = threadIdx.x;
  const int lane = tid & 63;
  const int wid = tid >> 6;
  const int wr = wid >> 1, wc = wid & 1;
  const int l15 = lane & 15, lg = lane >> 4;
  const int r0 = blockIdx.y * 128;
  const int c0 = blockIdx.x * 128;

  f32x4 acc[4][4];
#pragma unroll
  for (int mi = 0; mi < 4; ++mi)
#pragma unroll
    for (int ni = 0; ni < 4; ++ni)
#pragma unroll
      for (int j = 0; j < 4; ++j) acc[mi][ni][j] = 0.f;

  auto STAGE = [&](int buf, int k0) {
#pragma unroll
    for (int s = 0; s < 4; ++s) {
      const int c = s * 256 + tid;            // 16B-chunk id [0,1024)
      const int row = c >> 3;
      const int scol = (c & 7) ^ (row & 7);   // pre-swizzled source chunk
      gload_lds16(A + (size_t)(r0 + row) * K + k0 + scol * 8,
                  (char*)As[buf] + c * 16);
      gload_lds16(W + (size_t)(c0 + row) * K + k0 + scol * 8,
                  (char*)Ws[buf] + c * 16);
    }
  };

  const int nt = K >> 6;
  STAGE(0, 0);
  int cur = 0;
  for (int t = 0; t < nt; ++t) {
    __syncthreads();  // drains STAGE(cur); prev compute of cur^1 done
    if (t + 1 < nt) STAGE(cur ^ 1, (t + 1) * 64);
#pragma unroll
    for (int kk = 0; kk < 2; ++kk) {
      bf16x8 af[4], wf[4];
#pragma unroll
      for (int mi = 0; mi < 4; ++mi) {
        const int r = wr * 64 + mi * 16 + l15;
        af[mi] = *reinterpret_cast<const bf16x8*>(
            (char*)As[cur] + r * 128 + ((kk * 64 + lg * 16) ^ ((r & 7) << 4)));
      }
#pragma unroll
      for (int ni = 0; ni < 4; ++ni) {
        const int r = wc * 64 + ni * 16 + l15;
        wf[ni] = *reinterpret_cast<const bf16x8*>(
            (char*)Ws[cur] + r * 128 + ((kk * 64 + lg * 16) ^ ((r & 7) << 4)));
      }
#pragma unroll
      for (int mi = 0; mi < 4; ++mi)
#pragma unroll
        for (int ni = 0; ni < 4; ++ni)
          acc[mi][ni] = __builtin_amdgcn_mfma_f32_16x16x32_bf16(
              af[mi], wf[ni], acc[mi][ni], 0, 0, 0);
    }
    cur ^= 1;
  }

#pragma unroll
  for (int mi = 0; mi < 4; ++mi)
#pragma unroll
    for (int ni = 0; ni < 4; ++ni)
#pragma unroll
      for (int j = 0; j < 4; ++j) {
        const int row = r0 + wr * 64 + mi * 16 + lg * 4 + j;
        const int col = c0 + wc * 64 + ni * 16 + l15;
        const float v = acc[mi][ni][j];
        if constexpr (__is_same(OutT, float))
          C[(size_t)row * N + col] = v;
        else
          C[(size_t)row * N + col] = (bf16_t)v;
      }
}

// ---------------- fused RoPE + V transpose ----------------
__global__ __launch_bounds__(256) void rope_vtrans(
    const bf16_t* __restrict__ qkv, const float* __restrict__ fc,
    const float* __restrict__ fs, bf16_t* __restrict__ Qr,
    bf16_t* __restrict__ Kr, bf16_t* __restrict__ Vt) {
  __shared__ bf16_t L[64][68];
  const int tid = threadIdx.x;
  if (blockIdx.x < 4096) {
    const int n = blockIdx.x;
    const int b = n >> 11, t = n & 2047;
    const bf16_t* row = qkv + (size_t)n * 3072;
#pragma unroll
    for (int i = 0; i < 4; ++i) {
      const int p = i * 256 + tid;
      const int h = p >> 6, j = p & 63;
      const float t0 = (float)row[h * 128 + 2 * j];
      const float t1 = (float)row[h * 128 + 2 * j + 1];
      const float c = fc[t * 64 + j], s = fs[t * 64 + j];
      const size_t dst = ((size_t)(b * 16 + h) * 2048 + t) * 128 + 2 * j;
      Qr[dst] = (bf16_t)((t0 * c - t1 * s) * SCALE_Q2);
      Qr[dst + 1] = (bf16_t)((t0 * s + t1 * c) * SCALE_Q2);
    }
    {
      const int kvh = tid >> 6, j = tid & 63;
      const float t0 = (float)row[2048 + kvh * 128 + 2 * j];
      const float t1 = (float)row[2048 + kvh * 128 + 2 * j + 1];
      const float c = fc[t * 64 + j], s = fs[t * 64 + j];
      const size_t dst = ((size_t)(b * 4 + kvh) * 2048 + t) * 128 + 2 * j;
      Kr[dst] = (bf16_t)(t0 * c - t1 * s);
      Kr[dst + 1] = (bf16_t)(t0 * s + t1 * c);
    }
  } else {
    const int bid = blockIdx.x - 4096;       // [0,512)
    const int tt = bid & 31;
    const int dt2 = (bid >> 5) & 1;
    const int bk = bid >> 6;
    const int b = bk >> 2, kvh = bk & 3;
    const int t0 = tt * 64, d0 = dt2 * 64;
    const int r = tid >> 4;
    const int c4 = (tid & 15) * 4;
#pragma unroll
    for (int it = 0; it < 4; ++it) {
      const int tl = r + it * 16;
      const int tp = (tl & ~15) |
                     ((tl & 3) | ((tl & 4) << 1) | ((tl & 8) >> 1));
      const bf16_t* src = qkv + (size_t)(b * 2048 + t0 + tl) * 3072 + 2560 +
                          kvh * 128 + d0 + c4;
      *reinterpret_cast<bf16x4*>(&L[tp][c4]) =
          *reinterpret_cast<const bf16x4*>(src);
    }
    __syncthreads();
#pragma unroll
    for (int it = 0; it < 4; ++it) {
      const int dr = r + it * 16;
      bf16x4 v;
#pragma unroll
      for (int j = 0; j < 4; ++j) v[j] = L[c4 + j][dr];
      *reinterpret_cast<bf16x4*>(Vt + ((size_t)bk * 128 + d0 + dr) * 2048 +
                                 t0 + c4) = v;
    }
  }
}

// ---------------- causal GQA flash attention (32x32 MFMA, swapped QK) ------
// Round-15 exact structure (best known: 84.4us): 4 waves x 32q, KVBLK=128,
// K dbuf 64KB, kf-pair QK^T + V ping-pong prefetch, VALU-tree lsum (r16's
// ones-MFMA lsum cost +5us: extra MFMAs on the PV-critical pipe).
#define VLOAD(buf, kf, kc)                                               \
  {                                                                      \
    _Pragma("unroll") for (int dtile_ = 0; dtile_ < 4; ++dtile_)         \
        buf[dtile_] = *reinterpret_cast<const bf16x8*>(                  \
            Vbase + (size_t)(dtile_ * 32 + l31) * 2048 + k0 + (kf) * 32 +\
            (kc) * 16 + hi * 8);                                         \
  }

__global__ __launch_bounds__(256, 2) void attn_fwd(
    const bf16_t* __restrict__ Qr, const bf16_t* __restrict__ Kr,
    const bf16_t* __restrict__ Vt, bf16_t* __restrict__ Oout) {
  __shared__ __align__(16) bf16_t Klds[2][128 * 128];
  const int tid = threadIdx.x;
  const int lane = tid & 63, w = tid >> 6;
  const int l31 = lane & 31, hi = lane >> 5;
  const int sidx = blockIdx.x >> 5;
  const int hb = blockIdx.x & 31;
  const int h = hb & 15, b = hb >> 4;
  const int kvh = h >> 2;
  const int st = (sidx < 8) ? (15 - sidx) : (sidx - 8);

  const bf16_t* Kbase = Kr + ((size_t)(b * 4 + kvh) * 2048) * 128;
  const bf16_t* Vbase = Vt + ((size_t)(b * 4 + kvh) * 128) * 2048;

  const int qbw = st * 128 + w * 32;
  const bf16_t* Qbase = Qr + ((size_t)(b * 16 + h) * 2048 + qbw + l31) * 128;

  auto STAGE = [&](bf16_t* dst, int kt) {
    const int k0s = kt * 128;
#pragma unroll
    for (int i = 0; i < 8; ++i) {
      const int c = i * 256 + tid;
      const int row = c >> 4;
      const int col = c & 15;
      const int scol = col ^ (row & 15);
      gload_lds16(Kbase + (size_t)(k0s + row) * 128 + scol * 8, dst + c * 8);
    }
  };

  STAGE(&Klds[0][0], 0);

  bf16x8 qf[8];
#pragma unroll
  for (int dt = 0; dt < 8; ++dt)
    qf[dt] = *reinterpret_cast<const bf16x8*>(Qbase + dt * 16 + hi * 8);

  f32x16 o[4];
#pragma unroll
  for (int d = 0; d < 4; ++d)
#pragma unroll
    for (int r = 0; r < 16; ++r) o[d][r] = 0.f;
  float lsum = 0.f;

  const int nt = st + 1;
  int cur = 0;
  for (int kt = 0; kt < nt; ++kt) {
    const int k0 = kt * 128;
    const bool last = (kt == nt - 1);
    const int kfmax = last ? w : 3;

    __syncthreads();  // prev STAGE drained; all readers of other buf done
    if (kt + 1 < nt) STAGE(&Klds[cur ^ 1][0], kt + 1);

    const char* KB = (const char*)&Klds[cur][0];

    // prologue V prefetch for kf=0 (lands under QK pair 0)
    bf16x8 vaA[4], vaB[4];
    VLOAD(vaA, 0, 0);
    VLOAD(vaB, 0, 1);

#pragma unroll
    for (int kp = 0; kp < 2; ++kp) {
      // ---- QK^T for kf pair (2kp, 2kp+1): two independent MFMA chains ----
      f32x16 sA, sB;
      __builtin_amdgcn_s_setprio(1);
      if (2 * kp <= kfmax) {
#pragma unroll
        for (int r = 0; r < 16; ++r) sA[r] = 0.f;
#pragma unroll
        for (int dt = 0; dt < 8; ++dt) {
          const int boff = ((2 * kp) * 32 + l31) * 256 +
                           ((dt * 32 + hi * 16) ^ ((l31 & 15) << 4));
          bf16x8 ka = *reinterpret_cast<const bf16x8*>(KB + boff);
          sA = __builtin_amdgcn_mfma_f32_32x32x16_bf16(ka, qf[dt], sA, 0, 0, 0);
        }
      }
      if (2 * kp + 1 <= kfmax) {
#pragma unroll
        for (int r = 0; r < 16; ++r) sB[r] = 0.f;
#pragma unroll
        for (int dt = 0; dt < 8; ++dt) {
          const int boff = ((2 * kp + 1) * 32 + l31) * 256 +
                           ((dt * 32 + hi * 16) ^ ((l31 & 15) << 4));
          bf16x8 ka = *reinterpret_cast<const bf16x8*>(KB + boff);
          sB = __builtin_amdgcn_mfma_f32_32x32x16_bf16(ka, qf[dt], sB, 0, 0, 0);
        }
      }
      __builtin_amdgcn_s_setprio(0);

      // ---- softmax + PV per kf in the pair ----
#pragma unroll
      for (int ki = 0; ki < 2; ++ki) {
        const int kf = 2 * kp + ki;
        if (kf <= kfmax) {
          const bool diag = last && (kf == w);
          float p[16];
#pragma unroll
          for (int r = 0; r < 16; ++r) {
            float e = exp2f(ki ? sB[r] : sA[r]);
            if (diag) {
              const int crow = (r & 3) + 8 * (r >> 2) + 4 * hi;
              if (crow > l31) e = 0.f;
            }
            p[r] = e;
          }
          const float t0 = (p[0] + p[1]) + (p[2] + p[3]);
          const float t1 = (p[4] + p[5]) + (p[6] + p[7]);
          const float t2 = (p[8] + p[9]) + (p[10] + p[11]);
          const float t3 = (p[12] + p[13]) + (p[14] + p[15]);
          lsum += (t0 + t1) + (t2 + t3);

          // kc0: consume vaA, then reload it for kf+1
          {
            unsigned int u0, u1, u2, u3;
            asm("v_cvt_pk_bf16_f32 %0, %1, %2" : "=v"(u0)
                : "v"(p[0]), "v"(p[1]));
            asm("v_cvt_pk_bf16_f32 %0, %1, %2" : "=v"(u1)
                : "v"(p[2]), "v"(p[3]));
            asm("v_cvt_pk_bf16_f32 %0, %1, %2" : "=v"(u2)
                : "v"(p[4]), "v"(p[5]));
            asm("v_cvt_pk_bf16_f32 %0, %1, %2" : "=v"(u3)
                : "v"(p[6]), "v"(p[7]));
            union { unsigned int u[4]; bf16x8 v; } pb;
            pb.u[0] = u0; pb.u[1] = u1; pb.u[2] = u2; pb.u[3] = u3;
            __builtin_amdgcn_s_setprio(1);
#pragma unroll
            for (int dtile = 0; dtile < 4; ++dtile)
              o[dtile] = __builtin_amdgcn_mfma_f32_32x32x16_bf16(
                  vaA[dtile], pb.v, o[dtile], 0, 0, 0);
            __builtin_amdgcn_s_setprio(0);
          }
          if (kf < kfmax) VLOAD(vaA, kf + 1, 0);

          // kc1: consume vaB, then reload it for kf+1
          {
            unsigned int u0, u1, u2, u3;
            asm("v_cvt_pk_bf16_f32 %0, %1, %2" : "=v"(u0)
                : "v"(p[8]), "v"(p[9]));
            asm("v_cvt_pk_bf16_f32 %0, %1, %2" : "=v"(u1)
                : "v"(p[10]), "v"(p[11]));
            asm("v_cvt_pk_bf16_f32 %0, %1, %2" : "=v"(u2)
                : "v"(p[12]), "v"(p[13]));
            asm("v_cvt_pk_bf16_f32 %0, %1, %2" : "=v"(u3)
                : "v"(p[14]), "v"(p[15]));
            union { unsigned int u[4]; bf16x8 v; } pb;
            pb.u[0] = u0; pb.u[1] = u1; pb.u[2] = u2; pb.u[3] = u3;
            __builtin_amdgcn_s_setprio(1);
#pragma unroll
            for (int dtile = 0; dtile < 4; ++dtile)
              o[dtile] = __builtin_amdgcn_mfma_f32_32x32x16_bf16(
                  vaB[dtile], pb.v, o[dtile], 0, 0, 0);
            __builtin_amdgcn_s_setprio(0);
          }
          if (kf < kfmax) VLOAD(vaB, kf + 1, 1);
        }
      }
    }
    cur ^= 1;
  }

  // ---- epilogue: normalize + store O^T (col=q, row=d) ----
  const float ltot = lsum + __shfl_xor(lsum, 32);
  const float inv = 1.f / ltot;
  bf16_t* Obase = Oout + ((size_t)b * 2048 + qbw + l31) * 2048 + h * 128;
#pragma unroll
  for (int dtile = 0; dtile < 4; ++dtile)
#pragma unroll
    for (int g = 0; g < 4; ++g) {
      bf16x4 stv;
#pragma unroll
      for (int j = 0; j < 4; ++j)
        stv[j] = (bf16_t)(o[dtile][g * 4 + j] * inv);
      *reinterpret_cast<bf16x4*>(Obase + dtile * 32 + 8 * g + 4 * hi) = stv;
    }
}

// ---------------- host launch ----------------
extern "C" void kernel_launch(void* const* d_in, const int* in_sizes, int n_in,
                              void* d_out, int out_size, void* d_ws,
                              size_t ws_size, hipStream_t stream) {
  const float* x  = (const float*)d_in[0];
  const float* wq = (const float*)d_in[1];
  const float* wk = (const float*)d_in[2];
  const float* wv = (const float*)d_in[3];
  const float* wo = (const float*)d_in[4];
  const float* fc = (const float*)d_in[5];
  const float* fs = (const float*)d_in[6];
  float* out = (float*)d_out;

  char* ws = (char*)d_ws;
  bf16_t* xb      = (bf16_t*)(ws + 0);
  bf16_t* wqkv    = (bf16_t*)(ws + 16777216);
  bf16_t* wo_b    = (bf16_t*)(ws + 29360128);
  bf16_t* qkv     = (bf16_t*)(ws + 37748736);
  bf16_t* Qr      = (bf16_t*)(ws + 62914560);
  bf16_t* Kr      = (bf16_t*)(ws + 79691776);
  bf16_t* Vt      = (bf16_t*)(ws + 83886080);
  bf16_t* attn_o  = xb;

  const int M = 4096;

  cvt_all<<<2048, 256, 0, stream>>>(x, wq, wk, wv, wo, xb, wqkv, wo_b);

  gemm_bt<bf16_t><<<dim3(3072 / 128, M / 128), 256, 0, stream>>>(
      xb, wqkv, qkv, M, 3072, 2048);

  rope_vtrans<<<4608, 256, 0, stream>>>(qkv, fc, fs, Qr, Kr, Vt);

  attn_fwd<<<512, 256, 0, stream>>>(Qr, Kr, Vt, attn_o);

  gemm_bt<float><<<dim3(2048 / 128, M / 128), 256, 0, stream>>>(
      attn_o, wo_b, out, M, 2048, 2048);
}